// Round 8
// baseline (238.565 us; speedup 1.0000x reference)
//
#include <hip/hip_runtime.h>

#define NODES 1430
#define GENE0 1421
#define NHEADS 9
#define BHIST 1024           // 16 waves/block (hist)
#define GMAX 64              // max bucketed in-edges per gene (Poisson(8) tail ~0)
#define BCAP 8192            // per-hist-block hit region (expected ~1230, 6.7x headroom)

__device__ __forceinline__ float frelu(float v) { return v > 0.f ? v : 0.f; }

// Pass 0 (new): gene detection only. Streams dst once with a pure-arithmetic
// test (no random loads except the 0.63% gene edges). Produces complete flagw
// BEFORE k_hist so hist can fuse the scatter's flag test.
__global__ __launch_bounds__(256, 8)
void k_pre(const int* __restrict__ esrc, const int* __restrict__ edst,
           int* __restrict__ gene_cnt, int* __restrict__ gene_src,
           unsigned int* __restrict__ flagw, int e) {
    const int tid = threadIdx.x;
    const int e4 = e >> 2;
    const int nb = gridDim.x;
    const int Q = (e4 + nb - 1) / nb;
    const int beg = blockIdx.x * Q;
    const int end = min(beg + Q, e4);
    const int len = (end > beg) ? (end - beg) : 0;
    const int4* ed4 = (const int4*)edst;
    const int eighth = len >> 3;

    auto proc = [&](int4 d4, int j4) {
#pragma unroll
        for (int c = 0; c < 4; c++) {
            unsigned int d = (unsigned int)((&d4.x)[c]);
            unsigned int graph = d / NODES;              // magic-mul div
            unsigned int pos = d - graph * NODES;
            if (pos >= GENE0) {
                int s = esrc[4 * j4 + c];                // rare random load
                atomicOr(&flagw[(unsigned)s >> 5], 1u << (s & 31));
                int g = (int)(graph * NHEADS + (pos - GENE0));
                int p = atomicAdd(gene_cnt + g, 1);
                if (p < GMAX) gene_src[(g << 6) + p] = s;
            }
        }
    };

    for (int i = tid; i < eighth; i += 256) {
        int j0 = beg + i;
        int4 v0 = ed4[j0];
        int4 v1 = ed4[j0 + eighth];
        int4 v2 = ed4[j0 + 2 * eighth];
        int4 v3 = ed4[j0 + 3 * eighth];
        int4 v4 = ed4[j0 + 4 * eighth];
        int4 v5 = ed4[j0 + 5 * eighth];
        int4 v6 = ed4[j0 + 6 * eighth];
        int4 v7 = ed4[j0 + 7 * eighth];
        proc(v0, j0);
        proc(v1, j0 + eighth);
        proc(v2, j0 + 2 * eighth);
        proc(v3, j0 + 3 * eighth);
        proc(v4, j0 + 4 * eighth);
        proc(v5, j0 + 5 * eighth);
        proc(v6, j0 + 6 * eighth);
        proc(v7, j0 + 7 * eighth);
    }
    for (int i = (eighth << 3) + tid; i < len; i += 256) {
        proc(ed4[beg + i], beg + i);
    }
    if (blockIdx.x == 0) {                               // tail edges (e % 4)
        for (int j = (e4 << 2) + tid; j < e; j += 256) {
            unsigned int d = (unsigned int)edst[j];
            unsigned int graph = d / NODES;
            unsigned int pos = d - graph * NODES;
            if (pos >= GENE0) {
                int s = esrc[j];
                atomicOr(&flagw[(unsigned)s >> 5], 1u << (s & 31));
                int g = (int)(graph * NHEADS + (pos - GENE0));
                int p = atomicAdd(gene_cnt + g, 1);
                if (p < GMAX) gene_src[(g << 6) + p] = s;
            }
        }
    }
}

// Pass 1: privatized LDS nibble histogram + FUSED scatter hit-compaction.
// Each edge's qualifying visit (rel<hb, exactly one block) additionally tests
// the now-complete flagw and compacts (src,dst) into a per-block region via
// an LDS counter. This deletes the standalone scatter scan (41-51 us).
__global__ __launch_bounds__(BHIST, 4)
void k_hist(const int* __restrict__ esrc, const int* __restrict__ edst,
            unsigned int* __restrict__ copies,      // [K][R*hwords]
            const unsigned int* __restrict__ flagw,
            int2* __restrict__ hits,                // [K*R][BCAP]
            int* __restrict__ bcnt,                 // [K*R]
            unsigned int* __restrict__ ocnt, int2* __restrict__ ohits,
            int e, int K, int R, int n, int hbins, int hwords) {
    extern __shared__ unsigned int lds[];
    __shared__ int bqn;
    int id = blockIdx.x;
    int k, r;
    if ((K & 7) == 0) {
        int xcd = id & 7;
        int slot = id >> 3;
        int cin = slot / R;
        k = xcd * (K >> 3) + cin;
        r = slot - cin * R;
    } else {
        k = id / R;
        r = id - k * R;
    }
    const int tid = threadIdx.x;
    {
        uint4* l4 = (uint4*)lds;
        const int hw4 = hwords >> 2;
        for (int w = tid; w < hw4; w += BHIST) l4[w] = make_uint4(0, 0, 0, 0);
    }
    if (tid == 0) bqn = 0;
    __syncthreads();

    int2* blkq = hits + (size_t)id * BCAP;
    const unsigned int lo = (unsigned int)r * (unsigned int)hbins;
    const unsigned int hb = (unsigned int)hbins;
    const int e4 = e >> 2;
    const int Q = (e4 + K - 1) / K;
    const int beg = k * Q;
    const int end = min(beg + Q, e4);
    const int4* ed4 = (const int4*)edst;
    const int len = (end > beg) ? (end - beg) : 0;
    const int eighth = len >> 3;

    auto proc = [&](int4 d4, int j4) {
#pragma unroll
        for (int c = 0; c < 4; c++) {
            unsigned int d = (unsigned int)((&d4.x)[c]);
            unsigned int rel = d - lo;
            if (rel < hb) {
                atomicAdd(&lds[rel >> 3], 1u << ((rel & 7u) * 4u));
                if ((flagw[d >> 5] >> (d & 31)) & 1u) {  // random 4B, ~5% hit
                    int s = esrc[4 * j4 + c];
                    int2 v = make_int2(s, (int)d);
                    int idx = atomicAdd(&bqn, 1);        // LDS atomic, cheap
                    if (idx < BCAP) blkq[idx] = v;
                    else { unsigned op = atomicAdd(ocnt, 1u); ohits[op] = v; }
                }
            }
        }
    };

    for (int i = tid; i < eighth; i += BHIST) {
        int j0 = beg + i;
        int4 v0 = ed4[j0];
        int4 v1 = ed4[j0 + eighth];
        int4 v2 = ed4[j0 + 2 * eighth];
        int4 v3 = ed4[j0 + 3 * eighth];
        int4 v4 = ed4[j0 + 4 * eighth];
        int4 v5 = ed4[j0 + 5 * eighth];
        int4 v6 = ed4[j0 + 6 * eighth];
        int4 v7 = ed4[j0 + 7 * eighth];
        proc(v0, j0);
        proc(v1, j0 + eighth);
        proc(v2, j0 + 2 * eighth);
        proc(v3, j0 + 3 * eighth);
        proc(v4, j0 + 4 * eighth);
        proc(v5, j0 + 5 * eighth);
        proc(v6, j0 + 6 * eighth);
        proc(v7, j0 + 7 * eighth);
    }
    for (int i = (eighth << 3) + tid; i < len; i += BHIST) {
        proc(ed4[beg + i], beg + i);
    }
    if (k == 0) {                                   // tail edges (e % 4)
        for (int j = (e4 << 2) + tid; j < e; j += BHIST) {
            unsigned int d = (unsigned int)edst[j];
            unsigned int rel = d - lo;
            if (rel < hb) {
                atomicAdd(&lds[rel >> 3], 1u << ((rel & 7u) * 4u));
                if ((flagw[d >> 5] >> (d & 31)) & 1u) {
                    int s = esrc[j];
                    int2 v = make_int2(s, (int)d);
                    int idx = atomicAdd(&bqn, 1);
                    if (idx < BCAP) blkq[idx] = v;
                    else { unsigned op = atomicAdd(ocnt, 1u); ohits[op] = v; }
                }
            }
        }
    }
    __syncthreads();
    if (tid == 0) bcnt[id] = min(bqn, BCAP);
    int wlimit = (n > (int)lo) ? ((n - (int)lo + 7) >> 3) : 0;
    if (wlimit > hwords) wlimit = hwords;
    int w4 = (wlimit + 3) >> 2;
    uint4* dst4 = (uint4*)(copies + ((size_t)k * R + r) * hwords);
    const uint4* l4 = (const uint4*)lds;
    for (int w = tid; w < w4; w += BHIST) dst4[w] = l4[w];
}

// Pass 2: SWAR-sum the K nibble copies -> dx={dinv,dinv*x}, t=0 (R7-proven).
__global__ void k_reduce(const unsigned int* __restrict__ copies,
                         const float* __restrict__ x,
                         float2* __restrict__ dx, float* __restrict__ t,
                         int n, int K, int Wtot) {
    int w = blockIdx.x * blockDim.x + threadIdx.x;
    if (w >= Wtot) return;
    int i0 = w << 3;
    if (i0 >= n) return;
    const unsigned int M = 0x0F0F0F0Fu;
    unsigned int ev[8] = {0, 0, 0, 0, 0, 0, 0, 0};
    unsigned int od[8] = {0, 0, 0, 0, 0, 0, 0, 0};
    int k = 0;
    for (; k + 8 <= K; k += 8) {
#pragma unroll
        for (int s = 0; s < 8; s++) {
            unsigned int u = copies[(size_t)(k + s) * Wtot + w];
            ev[s] += u & M; od[s] += (u >> 4) & M;
        }
    }
    for (; k < K; k++) {
        unsigned int u = copies[(size_t)k * Wtot + w];
        ev[0] += u & M; od[0] += (u >> 4) & M;
    }
    unsigned int evn = ((ev[0] + ev[1]) + (ev[2] + ev[3])) + ((ev[4] + ev[5]) + (ev[6] + ev[7]));
    unsigned int odd = ((od[0] + od[1]) + (od[2] + od[3])) + ((od[4] + od[5]) + (od[6] + od[7]));
    float v[8];
#pragma unroll
    for (int b = 0; b < 4; b++) {
        v[2 * b]     = (float)((evn >> (8 * b)) & 0xFFu);
        v[2 * b + 1] = (float)((odd >> (8 * b)) & 0xFFu);
    }
#pragma unroll
    for (int b = 0; b < 8; b++) v[b] = rsqrtf(v[b] + 1.f);
    float4 z4 = {0.f, 0.f, 0.f, 0.f};
    if (i0 + 7 < n) {
        float4 xa = *(const float4*)(x + i0);
        float4 xb = *(const float4*)(x + i0 + 4);
        float4 p0 = {v[0], v[0] * xa.x, v[1], v[1] * xa.y};
        float4 p1 = {v[2], v[2] * xa.z, v[3], v[3] * xa.w};
        float4 p2 = {v[4], v[4] * xb.x, v[5], v[5] * xb.y};
        float4 p3 = {v[6], v[6] * xb.z, v[7], v[7] * xb.w};
        float4* dst = (float4*)(dx + i0);
        dst[0] = p0; dst[1] = p1; dst[2] = p2; dst[3] = p3;
        *(float4*)(t + i0) = z4;
        *(float4*)(t + i0 + 4) = z4;
    } else {
        for (int b = 0; b < 8; b++)
            if (i0 + b < n) {
                dx[i0 + b] = make_float2(v[b], v[b] * x[i0 + b]);
                t[i0 + b] = 0.f;
            }
    }
}

// Pass 3 (new): drain the compacted hit lists -> t. ~295K ops total.
__global__ __launch_bounds__(256, 8)
void k_drain(const int2* __restrict__ hits, const int* __restrict__ bcnt,
             const int2* __restrict__ ohits, const unsigned int* __restrict__ ocnt,
             const float2* __restrict__ dx, float* __restrict__ t, int nbh) {
    int b = blockIdx.x;
    if (b < nbh) {
        int m = bcnt[b];
        const int2* rg = hits + (size_t)b * BCAP;
        for (int i = threadIdx.x; i < m; i += 256) {
            int2 sd = rg[i];
            atomicAdd(t + sd.y, dx[sd.x].y);
        }
    } else {
        int m = (int)*ocnt;                          // overflow (normally 0)
        int stride = (gridDim.x - nbh) * 256;
        for (int i = (b - nbh) * 256 + threadIdx.x; i < m; i += stride) {
            int2 sd = ohits[i];
            atomicAdd(t + sd.y, dx[sd.x].y);
        }
    }
}

// Pass 4: one wave per gene; tn computed in-register from gene_src (R7-proven).
__global__ void k_gene_final(const int* __restrict__ gene_cnt, const int* __restrict__ gene_src,
                             const float* __restrict__ t, const float2* __restrict__ dx,
                             const float* __restrict__ W1, const float* __restrict__ b1,
                             const float* __restrict__ W2, const float* __restrict__ b2,
                             const float* __restrict__ fw1, const float* __restrict__ fb1,
                             const float* __restrict__ fw2, const float* __restrict__ fb2,
                             float* __restrict__ out, int NG, int G) {
    int wid = (blockIdx.x * blockDim.x + threadIdx.x) >> 6;
    int lane = threadIdx.x & 63;
    if (wid >= NG) return;
    int g = wid;
    int graph = g / NHEADS;
    int head = g - graph * NHEADS;
    int node = graph * NODES + GENE0 + head;
    const int c = lane & 15;
    const int slot = lane >> 4;
    int cnt = min(gene_cnt[g], GMAX);

    float w1r[16], b1r[16], w2c[16];
#pragma unroll
    for (int kk = 0; kk < 16; kk++) {
        w1r[kk] = W1[kk];
        b1r[kk] = b1[kk];
        w2c[kk] = W2[kk * 16 + c];
    }
    float2 dn2 = dx[node];

    float acc = 0.f, tsum = 0.f;
    const int base = g << 6;
    for (int i = slot; i < cnt; i += 8) {
        int s0 = gene_src[base + i];
        int i1 = i + 4;
        int s1 = (i1 < cnt) ? gene_src[base + i1] : -1;
        float2 a2 = dx[s0];
        float ta = t[s0];
        float2 b2v = (s1 >= 0) ? dx[s1] : make_float2(0.f, 0.f);
        float tb = (s1 >= 0) ? t[s1] : 0.f;
        tsum += a2.y + b2v.y;
        {
            float us = a2.x * ta + a2.x * a2.y;
            float m = 0.f;
#pragma unroll
            for (int kk = 0; kk < 16; kk++)
                m += frelu(us * w1r[kk] + b1r[kk]) * w2c[kk];
            acc += a2.x * m;
        }
        if (s1 >= 0) {
            float us = b2v.x * tb + b2v.x * b2v.y;
            float m = 0.f;
#pragma unroll
            for (int kk = 0; kk < 16; kk++)
                m += frelu(us * w1r[kk] + b1r[kk]) * w2c[kk];
            acc += b2v.x * m;
        }
    }
    acc += __shfl_xor(acc, 16, 64);
    acc += __shfl_xor(acc, 32, 64);
    tsum += __shfl_xor(tsum, 16, 64);
    tsum += __shfl_xor(tsum, 32, 64);

    float dn = dn2.x;
    float un = dn * tsum + dn * dn2.y;
    float h2 = 0.f;
#pragma unroll
    for (int kk = 0; kk < 16; kk++)
        h2 += frelu(un * w1r[kk] + b1r[kk]) * w2c[kk];
    float h = frelu(dn * acc + dn * dn * h2 + b2[c]);

    float hv[16];
#pragma unroll
    for (int c2 = 0; c2 < 16; c2++) hv[c2] = __shfl(h, c2, 64);

    int kk = lane & 7;
    float z = fb1[head * 8 + kk];
#pragma unroll
    for (int c2 = 0; c2 < 16; c2++) z += hv[c2] * fw1[head * 128 + c2 * 8 + kk];
    float term = frelu(z) * fw2[head * 8 + kk];
    term += __shfl_xor(term, 1, 64);
    term += __shfl_xor(term, 2, 64);
    term += __shfl_xor(term, 4, 64);
    if (lane == 0) out[head * G + graph] = fb2[head] + term;
}

extern "C" void kernel_launch(void* const* d_in, const int* in_sizes, int n_in,
                              void* d_out, int out_size, void* d_ws, size_t ws_size,
                              hipStream_t stream) {
    const float* x   = (const float*)d_in[0];
    const int*   ei  = (const int*)d_in[1];
    const float* W1  = (const float*)d_in[3];
    const float* b1  = (const float*)d_in[4];
    const float* W2  = (const float*)d_in[5];
    const float* b2  = (const float*)d_in[6];
    const float* fw1 = (const float*)d_in[7];
    const float* fb1 = (const float*)d_in[8];
    const float* fw2 = (const float*)d_in[9];
    const float* fb2 = (const float*)d_in[10];

    int n = in_sizes[0];
    int e = in_sizes[1] / 2;
    int G = in_sizes[2] / NHEADS;
    int NG = G * NHEADS;
    const int* esrc = ei;
    const int* edst = ei + e;
    int nw = (n + 31) / 32;

    // One-time: 128 KB dynamic LDS for k_hist (proven working R1-R3).
    static int HB_RT = 0;
    if (HB_RT == 0) {
        hipError_t st = hipFuncSetAttribute(
            reinterpret_cast<const void*>(k_hist),
            hipFuncAttributeMaxDynamicSharedMemorySize, 131072);
        HB_RT = (st == hipSuccess) ? 262144 : 131072;
    }
    const int HB = HB_RT;
    const int HW = HB >> 3;

    char* ws = (char*)d_ws;
    size_t off = 0;
    auto alloc = [&](size_t bytes) {
        char* p = ws + off;
        off += (bytes + 255) & ~(size_t)255;
        return p;
    };
    int*   gene_cnt      = (int*)alloc((size_t)NG * 4);
    unsigned int* flagw  = (unsigned int*)alloc((size_t)nw * 4);
    unsigned int* ocnt   = (unsigned int*)alloc(4);
    size_t zero_bytes    = off;                              // ~110 KB memset
    int*    gene_src     = (int*)alloc((size_t)NG * GMAX * 4);
    float*  t            = (float*)alloc((size_t)n * 4);     // zeroed by k_reduce
    float2* dx           = (float2*)alloc((size_t)n * 8);
    size_t fixed         = off;

    int R = (n + HB - 1) / HB;
    size_t per_copy = (size_t)R * HW * 4;
    int K = 80;
    // reserve hits/bcnt/ohits alongside copies
    size_t extra = (size_t)K * R * BCAP * 8 + (size_t)K * R * 4 + (size_t)e * 8 + 1024;
    if (fixed + (size_t)K * per_copy + extra > ws_size) {
        size_t avail = (ws_size > fixed + extra) ? (ws_size - fixed - extra) : 0;
        int kfit = (int)(avail / per_copy);
        if (kfit >= 8) kfit &= ~7;
        K = kfit < 1 ? 1 : (kfit < K ? kfit : K);
    }
    int NBH = K * R;
    unsigned int* copies = (unsigned int*)alloc((size_t)K * per_copy);
    int2* hits           = (int2*)alloc((size_t)NBH * BCAP * 8);
    int*  bcnt           = (int*)alloc((size_t)NBH * 4);
    int2* ohits          = (int2*)alloc((size_t)e * 8);
    (void)n_in; (void)out_size;

    hipMemsetAsync(d_ws, 0, zero_bytes, stream);

    const int B = 256;
    k_pre<<<512, 256, 0, stream>>>(esrc, edst, gene_cnt, gene_src, flagw, e);
    size_t shmem = (size_t)HW * 4;
    k_hist<<<NBH, BHIST, shmem, stream>>>(esrc, edst, copies, flagw,
                                          hits, bcnt, ocnt, ohits,
                                          e, K, R, n, HB, HW);
    int Wtot = R * HW;
    k_reduce<<<(Wtot + B - 1) / B, B, 0, stream>>>(copies, x, dx, t, n, K, Wtot);
    k_drain<<<NBH + 8, 256, 0, stream>>>(hits, bcnt, ohits, ocnt, dx, t, NBH);
    int waves_blocks = (NG * 64 + B - 1) / B;
    k_gene_final<<<waves_blocks, B, 0, stream>>>(gene_cnt, gene_src, t, dx,
                                                 W1, b1, W2, b2,
                                                 fw1, fb1, fw2, fb2,
                                                 (float*)d_out, NG, G);
}

// Round 9
// 215.085 us; speedup vs baseline: 1.1092x; 1.1092x over previous
//
#include <hip/hip_runtime.h>

#define NODES 1430
#define GENE0 1421
#define NHEADS 9
#define BHIST 1024           // 16 waves/block (hist)
#define GMAX 64              // max bucketed in-edges per gene (Poisson(8) tail ~0)
#define BCAP 4096            // per-hist-block hit region (expected ~1230)
#define GCH 256              // graph-chunks for gene kernel (2 graphs/wave)

__device__ __forceinline__ float frelu(float v) { return v > 0.f ? v : 0.f; }

// Pass 0: gene detection. Streams dst once with a pure-arithmetic test;
// esrc fetched only for the 0.63% gene edges. Produces complete flagw
// BEFORE k_hist so hist can do its LDS-resident flag test.
__global__ __launch_bounds__(256, 8)
void k_pre(const int* __restrict__ esrc, const int* __restrict__ edst,
           int* __restrict__ gene_cnt, int* __restrict__ gene_src,
           unsigned int* __restrict__ flagw, int e) {
    const int tid = threadIdx.x;
    const int e4 = e >> 2;
    const int nb = gridDim.x;
    const int Q = (e4 + nb - 1) / nb;
    const int beg = blockIdx.x * Q;
    const int end = min(beg + Q, e4);
    const int len = (end > beg) ? (end - beg) : 0;
    const int4* ed4 = (const int4*)edst;
    const int eighth = len >> 3;

    auto proc = [&](int4 d4, int j4) {
#pragma unroll
        for (int c = 0; c < 4; c++) {
            unsigned int d = (unsigned int)((&d4.x)[c]);
            unsigned int graph = d / NODES;              // magic-mul div
            unsigned int pos = d - graph * NODES;
            if (pos >= GENE0) {
                int s = esrc[4 * j4 + c];                // rare random load
                atomicOr(&flagw[(unsigned)s >> 5], 1u << (s & 31));
                int g = (int)(graph * NHEADS + (pos - GENE0));
                int p = atomicAdd(gene_cnt + g, 1);
                if (p < GMAX) gene_src[(g << 6) + p] = s;
            }
        }
    };

    for (int i = tid; i < eighth; i += 256) {
        int j0 = beg + i;
        int4 v0 = ed4[j0];
        int4 v1 = ed4[j0 + eighth];
        int4 v2 = ed4[j0 + 2 * eighth];
        int4 v3 = ed4[j0 + 3 * eighth];
        int4 v4 = ed4[j0 + 4 * eighth];
        int4 v5 = ed4[j0 + 5 * eighth];
        int4 v6 = ed4[j0 + 6 * eighth];
        int4 v7 = ed4[j0 + 7 * eighth];
        proc(v0, j0);
        proc(v1, j0 + eighth);
        proc(v2, j0 + 2 * eighth);
        proc(v3, j0 + 3 * eighth);
        proc(v4, j0 + 4 * eighth);
        proc(v5, j0 + 5 * eighth);
        proc(v6, j0 + 6 * eighth);
        proc(v7, j0 + 7 * eighth);
    }
    for (int i = (eighth << 3) + tid; i < len; i += 256) {
        proc(ed4[beg + i], beg + i);
    }
    if (blockIdx.x == 0) {                               // tail edges (e % 4)
        for (int j = (e4 << 2) + tid; j < e; j += 256) {
            unsigned int d = (unsigned int)edst[j];
            unsigned int graph = d / NODES;
            unsigned int pos = d - graph * NODES;
            if (pos >= GENE0) {
                int s = esrc[j];
                atomicOr(&flagw[(unsigned)s >> 5], 1u << (s & 31));
                int g = (int)(graph * NHEADS + (pos - GENE0));
                int p = atomicAdd(gene_cnt + g, 1);
                if (p < GMAX) gene_src[(g << 6) + p] = s;
            }
        }
    }
}

// Pass 1: privatized LDS nibble histogram + LDS-RESIDENT flag test + hit
// compaction. Key change vs R8 (which cost +50 us): the flag test for the
// qualifying range is a ~0.2 cy/edge LDS read, not a ~5 cy/edge divergent
// global load. HBINS=245760 -> hist 120 KB + flag slice 30 KB = 150 KB LDS
// (gfx950 has 160 KiB/CU). Fallback (use_ldsf=0): R8's global-flag path.
__global__ __launch_bounds__(BHIST, 4)
void k_hist(const int* __restrict__ esrc, const int* __restrict__ edst,
            unsigned int* __restrict__ copies,      // [K][R*hwords]
            const unsigned int* __restrict__ flagw,
            int2* __restrict__ hits,                // [K*R][BCAP]
            int* __restrict__ bcnt,                 // [K*R]
            unsigned int* __restrict__ ocnt, int2* __restrict__ ohits,
            int e, int K, int R, int n, int hbins, int hwords,
            int fwords, int use_ldsf) {
    extern __shared__ unsigned int lds[];
    __shared__ int bqn;
    int id = blockIdx.x;
    int k, r;
    if ((K & 7) == 0) {
        int xcd = id & 7;
        int slot = id >> 3;
        int cin = slot / R;
        k = xcd * (K >> 3) + cin;
        r = slot - cin * R;
    } else {
        k = id / R;
        r = id - k * R;
    }
    const int tid = threadIdx.x;
    unsigned int* lf = lds + hwords;                // flag slice (if use_ldsf)
    {
        uint4* l4 = (uint4*)lds;
        const int hw4 = hwords >> 2;
        for (int w = tid; w < hw4; w += BHIST) l4[w] = make_uint4(0, 0, 0, 0);
    }
    if (use_ldsf) {
        // load this range's 30KB bitmap slice: flag bits for nodes [lo,lo+hb)
        const uint4* g4 = (const uint4*)(flagw + (size_t)r * fwords);
        uint4* l4 = (uint4*)lf;
        const int fw4 = fwords >> 2;
        for (int w = tid; w < fw4; w += BHIST) l4[w] = g4[w];
    }
    if (tid == 0) bqn = 0;
    __syncthreads();

    int2* blkq = hits + (size_t)id * BCAP;
    const unsigned int lo = (unsigned int)r * (unsigned int)hbins;
    const unsigned int hb = (unsigned int)hbins;
    const int e4 = e >> 2;
    const int Q = (e4 + K - 1) / K;
    const int beg = k * Q;
    const int end = min(beg + Q, e4);
    const int4* ed4 = (const int4*)edst;
    const int len = (end > beg) ? (end - beg) : 0;
    const int eighth = len >> 3;

    auto proc = [&](int4 d4, int j4) {
#pragma unroll
        for (int c = 0; c < 4; c++) {
            unsigned int d = (unsigned int)((&d4.x)[c]);
            unsigned int rel = d - lo;
            if (rel < hb) {
                atomicAdd(&lds[rel >> 3], 1u << ((rel & 7u) * 4u));
                unsigned int fbit = use_ldsf
                    ? (lf[rel >> 5] >> (rel & 31))
                    : (flagw[d >> 5] >> (d & 31));
                if (fbit & 1u) {                         // ~5% hit
                    int s = esrc[4 * j4 + c];
                    int2 v = make_int2(s, (int)d);
                    int idx = atomicAdd(&bqn, 1);        // LDS atomic
                    if (idx < BCAP) blkq[idx] = v;
                    else { unsigned op = atomicAdd(ocnt, 1u); ohits[op] = v; }
                }
            }
        }
    };

    for (int i = tid; i < eighth; i += BHIST) {
        int j0 = beg + i;
        int4 v0 = ed4[j0];
        int4 v1 = ed4[j0 + eighth];
        int4 v2 = ed4[j0 + 2 * eighth];
        int4 v3 = ed4[j0 + 3 * eighth];
        int4 v4 = ed4[j0 + 4 * eighth];
        int4 v5 = ed4[j0 + 5 * eighth];
        int4 v6 = ed4[j0 + 6 * eighth];
        int4 v7 = ed4[j0 + 7 * eighth];
        proc(v0, j0);
        proc(v1, j0 + eighth);
        proc(v2, j0 + 2 * eighth);
        proc(v3, j0 + 3 * eighth);
        proc(v4, j0 + 4 * eighth);
        proc(v5, j0 + 5 * eighth);
        proc(v6, j0 + 6 * eighth);
        proc(v7, j0 + 7 * eighth);
    }
    for (int i = (eighth << 3) + tid; i < len; i += BHIST) {
        proc(ed4[beg + i], beg + i);
    }
    if (k == 0) {                                   // tail edges (e % 4)
        for (int j = (e4 << 2) + tid; j < e; j += BHIST) {
            unsigned int d = (unsigned int)edst[j];
            unsigned int rel = d - lo;
            if (rel < hb) {
                atomicAdd(&lds[rel >> 3], 1u << ((rel & 7u) * 4u));
                unsigned int fbit = use_ldsf
                    ? (lf[rel >> 5] >> (rel & 31))
                    : (flagw[d >> 5] >> (d & 31));
                if (fbit & 1u) {
                    int s = esrc[j];
                    int2 v = make_int2(s, (int)d);
                    int idx = atomicAdd(&bqn, 1);
                    if (idx < BCAP) blkq[idx] = v;
                    else { unsigned op = atomicAdd(ocnt, 1u); ohits[op] = v; }
                }
            }
        }
    }
    __syncthreads();
    if (tid == 0) bcnt[id] = min(bqn, BCAP);
    int wlimit = (n > (int)lo) ? ((n - (int)lo + 7) >> 3) : 0;
    if (wlimit > hwords) wlimit = hwords;
    int w4 = (wlimit + 3) >> 2;
    uint4* dst4 = (uint4*)(copies + ((size_t)k * R + r) * hwords);
    const uint4* l4 = (const uint4*)lds;
    for (int w = tid; w < w4; w += BHIST) dst4[w] = l4[w];
}

// Pass 2: SWAR-sum the K nibble copies -> dx={dinv,dinv*x}, t=0.
__global__ void k_reduce(const unsigned int* __restrict__ copies,
                         const float* __restrict__ x,
                         float2* __restrict__ dx, float* __restrict__ t,
                         int n, int K, int Wtot) {
    int w = blockIdx.x * blockDim.x + threadIdx.x;
    if (w >= Wtot) return;
    int i0 = w << 3;
    if (i0 >= n) return;
    const unsigned int M = 0x0F0F0F0Fu;
    unsigned int ev[8] = {0, 0, 0, 0, 0, 0, 0, 0};
    unsigned int od[8] = {0, 0, 0, 0, 0, 0, 0, 0};
    int k = 0;
    for (; k + 8 <= K; k += 8) {
#pragma unroll
        for (int s = 0; s < 8; s++) {
            unsigned int u = copies[(size_t)(k + s) * Wtot + w];
            ev[s] += u & M; od[s] += (u >> 4) & M;
        }
    }
    for (; k < K; k++) {
        unsigned int u = copies[(size_t)k * Wtot + w];
        ev[0] += u & M; od[0] += (u >> 4) & M;
    }
    unsigned int evn = ((ev[0] + ev[1]) + (ev[2] + ev[3])) + ((ev[4] + ev[5]) + (ev[6] + ev[7]));
    unsigned int odd = ((od[0] + od[1]) + (od[2] + od[3])) + ((od[4] + od[5]) + (od[6] + od[7]));
    float v[8];
#pragma unroll
    for (int b = 0; b < 4; b++) {
        v[2 * b]     = (float)((evn >> (8 * b)) & 0xFFu);
        v[2 * b + 1] = (float)((odd >> (8 * b)) & 0xFFu);
    }
#pragma unroll
    for (int b = 0; b < 8; b++) v[b] = rsqrtf(v[b] + 1.f);
    float4 z4 = {0.f, 0.f, 0.f, 0.f};
    if (i0 + 7 < n) {
        float4 xa = *(const float4*)(x + i0);
        float4 xb = *(const float4*)(x + i0 + 4);
        float4 p0 = {v[0], v[0] * xa.x, v[1], v[1] * xa.y};
        float4 p1 = {v[2], v[2] * xa.z, v[3], v[3] * xa.w};
        float4 p2 = {v[4], v[4] * xb.x, v[5], v[5] * xb.y};
        float4 p3 = {v[6], v[6] * xb.z, v[7], v[7] * xb.w};
        float4* dst = (float4*)(dx + i0);
        dst[0] = p0; dst[1] = p1; dst[2] = p2; dst[3] = p3;
        *(float4*)(t + i0) = z4;
        *(float4*)(t + i0 + 4) = z4;
    } else {
        for (int b = 0; b < 8; b++)
            if (i0 + b < n) {
                dx[i0 + b] = make_float2(v[b], v[b] * x[i0 + b]);
                t[i0 + b] = 0.f;
            }
    }
}

// Pass 3: drain the compacted hit lists -> t. ~293K atomics total.
__global__ __launch_bounds__(256, 8)
void k_drain(const int2* __restrict__ hits, const int* __restrict__ bcnt,
             const int2* __restrict__ ohits, const unsigned int* __restrict__ ocnt,
             const float2* __restrict__ dx, float* __restrict__ t, int nbh) {
    int b = blockIdx.x;
    if (b < nbh) {
        int m = bcnt[b];
        const int2* rg = hits + (size_t)b * BCAP;
        for (int i = threadIdx.x; i < m; i += 256) {
            int2 sd = rg[i];
            atomicAdd(t + sd.y, dx[sd.x].y);
        }
    } else {
        int m = (int)*ocnt;                          // overflow (normally 0)
        int stride = (gridDim.x - nbh) * 256;
        for (int i = (b - nbh) * 256 + threadIdx.x; i < m; i += stride) {
            int2 sd = ohits[i];
            atomicAdd(t + sd.y, dx[sd.x].y);
        }
    }
}

// Pass 4: gene final, head-major waves. Each wave owns one head and loops
// G/GCH graphs, so ALL weight loads (w1r/b1r/w2c + head-dependent fw1/fb1/
// fw2) hoist out of the per-gene loop. tn computed in-register (R7-proven).
__global__ __launch_bounds__(256)
void k_gene_final(const int* __restrict__ gene_cnt, const int* __restrict__ gene_src,
                  const float* __restrict__ t, const float2* __restrict__ dx,
                  const float* __restrict__ W1, const float* __restrict__ b1,
                  const float* __restrict__ W2, const float* __restrict__ b2,
                  const float* __restrict__ fw1, const float* __restrict__ fb1,
                  const float* __restrict__ fw2, const float* __restrict__ fb2,
                  float* __restrict__ out, int G) {
    int w = (blockIdx.x * blockDim.x + threadIdx.x) >> 6;
    int lane = threadIdx.x & 63;
    int head = w / GCH;
    int chunk = w - head * GCH;
    if (head >= NHEADS) return;
    const int c = lane & 15;
    const int slot = lane >> 4;
    const int kk = lane & 7;

    float w1r[16], b1r[16], w2c[16], fw1r[16];
#pragma unroll
    for (int i = 0; i < 16; i++) {
        w1r[i] = W1[i];
        b1r[i] = b1[i];
        w2c[i] = W2[i * 16 + c];
        fw1r[i] = fw1[head * 128 + i * 8 + kk];
    }
    float b2c  = b2[c];
    float fb1h = fb1[head * 8 + kk];
    float fw2h = fw2[head * 8 + kk];
    float fb2h = fb2[head];

    for (int graph = chunk; graph < G; graph += GCH) {
        int g = graph * NHEADS + head;
        int node = graph * NODES + GENE0 + head;
        int cnt = min(gene_cnt[g], GMAX);
        float2 dn2 = dx[node];

        float acc = 0.f, tsum = 0.f;
        const int base = g << 6;
        for (int i = slot; i < cnt; i += 8) {
            int s0 = gene_src[base + i];
            int i1 = i + 4;
            int s1 = (i1 < cnt) ? gene_src[base + i1] : -1;
            float2 a2 = dx[s0];
            float ta = t[s0];
            float2 b2v = (s1 >= 0) ? dx[s1] : make_float2(0.f, 0.f);
            float tb = (s1 >= 0) ? t[s1] : 0.f;
            tsum += a2.y + b2v.y;
            {
                float us = a2.x * ta + a2.x * a2.y;
                float m = 0.f;
#pragma unroll
                for (int q = 0; q < 16; q++)
                    m += frelu(us * w1r[q] + b1r[q]) * w2c[q];
                acc += a2.x * m;
            }
            if (s1 >= 0) {
                float us = b2v.x * tb + b2v.x * b2v.y;
                float m = 0.f;
#pragma unroll
                for (int q = 0; q < 16; q++)
                    m += frelu(us * w1r[q] + b1r[q]) * w2c[q];
                acc += b2v.x * m;
            }
        }
        acc += __shfl_xor(acc, 16, 64);
        acc += __shfl_xor(acc, 32, 64);
        tsum += __shfl_xor(tsum, 16, 64);
        tsum += __shfl_xor(tsum, 32, 64);

        float dn = dn2.x;
        float un = dn * tsum + dn * dn2.y;
        float h2 = 0.f;
#pragma unroll
        for (int q = 0; q < 16; q++)
            h2 += frelu(un * w1r[q] + b1r[q]) * w2c[q];
        float h = frelu(dn * acc + dn * dn * h2 + b2c);

        float hv[16];
#pragma unroll
        for (int c2 = 0; c2 < 16; c2++) hv[c2] = __shfl(h, c2, 64);

        float z = fb1h;
#pragma unroll
        for (int c2 = 0; c2 < 16; c2++) z += hv[c2] * fw1r[c2];
        float term = frelu(z) * fw2h;
        term += __shfl_xor(term, 1, 64);
        term += __shfl_xor(term, 2, 64);
        term += __shfl_xor(term, 4, 64);
        if (lane == 0) out[head * G + graph] = fb2h + term;
    }
}

extern "C" void kernel_launch(void* const* d_in, const int* in_sizes, int n_in,
                              void* d_out, int out_size, void* d_ws, size_t ws_size,
                              hipStream_t stream) {
    const float* x   = (const float*)d_in[0];
    const int*   ei  = (const int*)d_in[1];
    const float* W1  = (const float*)d_in[3];
    const float* b1  = (const float*)d_in[4];
    const float* W2  = (const float*)d_in[5];
    const float* b2  = (const float*)d_in[6];
    const float* fw1 = (const float*)d_in[7];
    const float* fb1 = (const float*)d_in[8];
    const float* fw2 = (const float*)d_in[9];
    const float* fb2 = (const float*)d_in[10];

    int n = in_sizes[0];
    int e = in_sizes[1] / 2;
    int G = in_sizes[2] / NHEADS;
    int NG = G * NHEADS;
    const int* esrc = ei;
    const int* edst = ei + e;
    int nw = (n + 31) / 32;

    // One-time LDS attribute: primary 150 KB (120 KB hist + 30 KB flag slice);
    // fallback 128 KB with global flag test (R8-proven-correct path).
    static int HB_RT = 0;
    static int LDSF = 0;
    if (HB_RT == 0) {
        hipError_t st = hipFuncSetAttribute(
            reinterpret_cast<const void*>(k_hist),
            hipFuncAttributeMaxDynamicSharedMemorySize, 153600);
        if (st == hipSuccess) { HB_RT = 245760; LDSF = 1; }
        else {
            hipFuncSetAttribute(
                reinterpret_cast<const void*>(k_hist),
                hipFuncAttributeMaxDynamicSharedMemorySize, 131072);
            HB_RT = 262144; LDSF = 0;
        }
    }
    const int HB = HB_RT;
    const int HW = HB >> 3;            // nibble words
    const int FW = HB >> 5;            // flag-slice words

    char* ws = (char*)d_ws;
    size_t off = 0;
    auto alloc = [&](size_t bytes) {
        char* p = ws + off;
        off += (bytes + 255) & ~(size_t)255;
        return p;
    };
    int*   gene_cnt      = (int*)alloc((size_t)NG * 4);
    unsigned int* flagw  = (unsigned int*)alloc((size_t)nw * 4);
    unsigned int* ocnt   = (unsigned int*)alloc(4);
    size_t zero_bytes    = off;                              // ~110 KB memset
    int*    gene_src     = (int*)alloc((size_t)NG * GMAX * 4);
    float*  t            = (float*)alloc((size_t)n * 4);     // zeroed by k_reduce
    float2* dx           = (float2*)alloc((size_t)n * 8);
    size_t fixed         = off;

    int R = (n + HB - 1) / HB;                               // 3
    size_t per_copy = (size_t)R * HW * 4;
    int K = 80;
    size_t extra = (size_t)K * R * BCAP * 8 + (size_t)K * R * 4 + (size_t)e * 8 + 1024;
    if (fixed + (size_t)K * per_copy + extra > ws_size) {
        size_t avail = (ws_size > fixed + extra) ? (ws_size - fixed - extra) : 0;
        int kfit = (int)(avail / per_copy);
        if (kfit >= 8) kfit &= ~7;
        K = kfit < 1 ? 1 : (kfit < K ? kfit : K);
    }
    int NBH = K * R;
    unsigned int* copies = (unsigned int*)alloc((size_t)K * per_copy);
    int2* hits           = (int2*)alloc((size_t)NBH * BCAP * 8);
    int*  bcnt           = (int*)alloc((size_t)NBH * 4);
    int2* ohits          = (int2*)alloc((size_t)e * 8);
    (void)n_in; (void)out_size;

    hipMemsetAsync(d_ws, 0, zero_bytes, stream);

    const int B = 256;
    k_pre<<<512, 256, 0, stream>>>(esrc, edst, gene_cnt, gene_src, flagw, e);
    size_t shmem = (size_t)HW * 4 + (LDSF ? (size_t)FW * 4 : 0);
    k_hist<<<NBH, BHIST, shmem, stream>>>(esrc, edst, copies, flagw,
                                          hits, bcnt, ocnt, ohits,
                                          e, K, R, n, HB, HW, FW, LDSF);
    int Wtot = R * HW;
    k_reduce<<<(Wtot + B - 1) / B, B, 0, stream>>>(copies, x, dx, t, n, K, Wtot);
    k_drain<<<NBH + 8, 256, 0, stream>>>(hits, bcnt, ohits, ocnt, dx, t, NBH);
    int gf_blocks = (NHEADS * GCH * 64) / 256;               // 576
    k_gene_final<<<gf_blocks, B, 0, stream>>>(gene_cnt, gene_src, t, dx,
                                              W1, b1, W2, b2,
                                              fw1, fb1, fw2, fb2,
                                              (float*)d_out, G);
}